// Round 5
// baseline (95.632 us; speedup 1.0000x reference)
//
#include <hip/hip_runtime.h>
#include <hip/hip_bf16.h>

typedef __bf16 bf16_t;
typedef bf16_t bf16x8 __attribute__((ext_vector_type(8)));
typedef float  f32x4  __attribute__((ext_vector_type(4)));

constexpr int M_TOT = 65536;   // B*S
constexpr int N_TOT = 512;     // E
constexpr int K_TOT = 512;     // E
constexpr int BM = 128, BN = 128, BK = 64;
constexpr int NT = K_TOT / BK; // 8 K-tiles

__device__ inline void gload_lds16(const void* g, void* l) {
    __builtin_amdgcn_global_load_lds(
        (const __attribute__((address_space(1))) void*)g,
        (__attribute__((address_space(3))) void*)l, 16, 0, 0);
}

// W (f32 [N][K]) -> bf16, chunk-XOR-swizzled: main kernel global_load_lds's it
// LINEARLY, reads back with chunk XOR. Wws[n][kt*64+(ck^(n&7))*8+j]=bf16(W[n][kt*64+ck*8+j])
__global__ __launch_bounds__(256)
void convert_W(const float* __restrict__ W, bf16_t* __restrict__ Wws)
{
    const int g  = blockIdx.x * 256 + threadIdx.x;
    const int n  = g >> 6;
    const int c  = g & 63;
    const int kt = c >> 3, ck = c & 7;
    const float4* src = reinterpret_cast<const float4*>(W + (size_t)n * K_TOT + c * 8);
    float4 v0 = src[0], v1 = src[1];
    bf16x8 b;
    b[0] = (bf16_t)v0.x; b[1] = (bf16_t)v0.y; b[2] = (bf16_t)v0.z; b[3] = (bf16_t)v0.w;
    b[4] = (bf16_t)v1.x; b[5] = (bf16_t)v1.y; b[6] = (bf16_t)v1.z; b[7] = (bf16_t)v1.w;
    const int dc = kt * 64 + ((ck ^ (n & 7)) * 8);
    *reinterpret_cast<bf16x8*>(Wws + (size_t)n * K_TOT + dc) = b;
}

// out[m,n] = sum_k cos(x[m,k] + phi[k%8]) * W[n,k] + bias[n]
// Structure: waves all-in-M (wave owns 32 M-rows x 128 N-cols). A never touches
// LDS: x -> regs -> cos -> MFMA A-frags directly. B double-buffered in LDS via
// global_load_lds from pre-swizzled Wws; ONE barrier/K-step, counted
// vmcnt(8) (drains 4 B-loads only; 8 x-prefetch loads stay in flight).
// (256,3): ~148 regs/thread incl. 64 acc. (256,5) spilled catastrophically (R3).
template<bool USE_WS>
__global__ __launch_bounds__(256, 3)
void qattn_fused_gemm(const float* __restrict__ x,
                      const float* __restrict__ phi,
                      const float* __restrict__ W,
                      const bf16_t* __restrict__ Wws,
                      const float* __restrict__ bias,
                      float* __restrict__ out)
{
    __shared__ bf16_t Bs[2][BN][BK];   // 32 KB double-buffered B

    const int tid  = threadIdx.x;
    const int lane = tid & 63;
    const int wave = tid >> 6;

    // XCD-bijective swizzle: 4 blocks sharing an x-panel on one XCD's L2.
    const int xcd = blockIdx.x & 7;
    const int idx = blockIdx.x >> 3;
    const int wid = xcd * 256 + idx;
    const int bm  = (wid >> 2) * BM;
    const int bn  = (wid & 3)  * BN;

    // phi broadcast (uniform -> SGPRs). (k & 7) == (elem index 0..7) for our frags.
    float ph[8];
    #pragma unroll
    for (int j = 0; j < 8; ++j) ph[j] = phi[j];

    const int frow = lane & 15;          // fragment row (m) / B n-row
    const int fk   = (lane >> 4) * 8;    // fragment k-offset

    // this lane's A rows: bm + wave*32 + mi*16 + frow; cols k0 + kk*32 + fk
    const float* xb = x + (size_t)(bm + wave * 32 + frow) * K_TOT + fk;

    f32x4  acc[2][8] = {};
    float4 pa[8];                        // x(t) in flight: [mi][kk][half]

    // ---- prologue: B(0) gloads FIRST (oldest in vmcnt FIFO), then x(0) ----
    if constexpr (USE_WS) {
        #pragma unroll
        for (int i = 0; i < 4; ++i) {
            const bf16_t* src = Wws + (size_t)(bn + wave * 32 + i * 8 + (lane >> 3)) * K_TOT
                                + (lane & 7) * 8;
            gload_lds16(src, &Bs[0][0][0] + wave * 2048 + i * 512);
        }
        __builtin_amdgcn_sched_barrier(0);   // pin: x-loads must not hoist above B
    } else {
        const int brow = tid >> 1;
        #pragma unroll
        for (int i = 0; i < 4; ++i) {
            const int ck = (tid & 1) * 4 + i;
            const float4* s = reinterpret_cast<const float4*>(
                W + (size_t)(bn + brow) * K_TOT + ck * 8);
            float4 v0 = s[0], v1 = s[1];
            bf16x8 b;
            b[0] = (bf16_t)v0.x; b[1] = (bf16_t)v0.y; b[2] = (bf16_t)v0.z; b[3] = (bf16_t)v0.w;
            b[4] = (bf16_t)v1.x; b[5] = (bf16_t)v1.y; b[6] = (bf16_t)v1.z; b[7] = (bf16_t)v1.w;
            *reinterpret_cast<bf16x8*>(&Bs[0][brow][(ck ^ (brow & 7)) * 8]) = b;
        }
    }
    #pragma unroll
    for (int f = 0; f < 8; ++f) {
        const int mi = f >> 2, kk = (f >> 1) & 1, h = f & 1;
        pa[f] = *reinterpret_cast<const float4*>(xb + mi * 16 * K_TOT + kk * 32 + h * 4);
    }
    if constexpr (USE_WS)
        asm volatile("s_waitcnt vmcnt(8) lgkmcnt(0)\n\ts_barrier" ::: "memory");
    else
        asm volatile("s_waitcnt lgkmcnt(0)\n\ts_barrier" ::: "memory");

    #pragma unroll
    for (int t = 0; t < NT; ++t) {
        const int cur  = t & 1;
        const bool last = (t == NT - 1);
        const int kn   = (t + 1) * BK;

        // ---- stage B(t+1) into buf[cur^1] (skipped on last iter: no dead
        //      loads -> vmcnt math exact, no in-flight LDS-DMA at endpgm) ----
        if (!last) {
            if constexpr (USE_WS) {
                #pragma unroll
                for (int i = 0; i < 4; ++i) {
                    const bf16_t* src = Wws
                        + (size_t)(bn + wave * 32 + i * 8 + (lane >> 3)) * K_TOT
                        + kn + (lane & 7) * 8;
                    gload_lds16(src, &Bs[cur ^ 1][0][0] + wave * 2048 + i * 512);
                }
                __builtin_amdgcn_sched_barrier(0);
            } else {
                const int brow = tid >> 1;
                #pragma unroll
                for (int i = 0; i < 4; ++i) {
                    const int ck = (tid & 1) * 4 + i;
                    const float4* s = reinterpret_cast<const float4*>(
                        W + (size_t)(bn + brow) * K_TOT + kn + ck * 8);
                    float4 v0 = s[0], v1 = s[1];
                    bf16x8 b;
                    b[0] = (bf16_t)v0.x; b[1] = (bf16_t)v0.y; b[2] = (bf16_t)v0.z; b[3] = (bf16_t)v0.w;
                    b[4] = (bf16_t)v1.x; b[5] = (bf16_t)v1.y; b[6] = (bf16_t)v1.z; b[7] = (bf16_t)v1.w;
                    *reinterpret_cast<bf16x8*>(&Bs[cur ^ 1][brow][(ck ^ (brow & 7)) * 8]) = b;
                }
            }
        }

        // ---- cos: pa(t) -> A-fragments in registers ----
        bf16x8 af[2][2];
        #pragma unroll
        for (int f = 0; f < 8; ++f) {
            const int mi = f >> 2, kk = (f >> 1) & 1, h = f & 1;
            af[mi][kk][h * 4 + 0] = (bf16_t)__cosf(pa[f].x + ph[h * 4 + 0]);
            af[mi][kk][h * 4 + 1] = (bf16_t)__cosf(pa[f].y + ph[h * 4 + 1]);
            af[mi][kk][h * 4 + 2] = (bf16_t)__cosf(pa[f].z + ph[h * 4 + 2]);
            af[mi][kk][h * 4 + 3] = (bf16_t)__cosf(pa[f].w + ph[h * 4 + 3]);
        }

        // ---- issue x(t+1) (stays in flight across the barrier) ----
        if (!last) {
            #pragma unroll
            for (int f = 0; f < 8; ++f) {
                const int mi = f >> 2, kk = (f >> 1) & 1, h = f & 1;
                pa[f] = *reinterpret_cast<const float4*>(
                    xb + mi * 16 * K_TOT + kn + kk * 32 + h * 4);
            }
        }

        // ---- compute: wave reads all 128 B-rows, 32 MFMAs ----
        #pragma unroll
        for (int kk = 0; kk < 2; ++kk) {
            #pragma unroll
            for (int nh = 0; nh < 2; ++nh) {
                bf16x8 bfr[4];
                #pragma unroll
                for (int nj = 0; nj < 4; ++nj) {
                    const int r = (nh * 4 + nj) * 16 + frow;
                    const int c = (kk * 32 + fk) ^ ((r & 7) << 3);
                    bfr[nj] = *reinterpret_cast<const bf16x8*>(&Bs[cur][r][c]);
                }
                #pragma unroll
                for (int mi = 0; mi < 2; ++mi)
                    #pragma unroll
                    for (int nj = 0; nj < 4; ++nj)
                        acc[mi][nh * 4 + nj] = __builtin_amdgcn_mfma_f32_16x16x32_bf16(
                            af[mi][kk], bfr[nj], acc[mi][nh * 4 + nj], 0, 0, 0);
            }
        }

        // ---- single barrier/step: drain 4 B-gloads (oldest) + my LDS ops;
        //      the 8 x(t+1) loads remain in flight ----
        if (!last) {
            if constexpr (USE_WS)
                asm volatile("s_waitcnt vmcnt(8) lgkmcnt(0)\n\ts_barrier" ::: "memory");
            else
                asm volatile("s_waitcnt lgkmcnt(0)\n\ts_barrier" ::: "memory");
        }
    }

    // ---- epilogue: C/D map col=lane&15, row=(lane>>4)*4+i ----
    #pragma unroll
    for (int ni = 0; ni < 8; ++ni) {
        const int c  = bn + ni * 16 + frow;
        const float bv = bias[c];
        #pragma unroll
        for (int mi = 0; mi < 2; ++mi) {
            const int r0 = bm + wave * 32 + mi * 16 + (lane >> 4) * 4;
            #pragma unroll
            for (int i = 0; i < 4; ++i)
                out[(size_t)(r0 + i) * N_TOT + c] = acc[mi][ni][i] + bv;
        }
    }
}

extern "C" void kernel_launch(void* const* d_in, const int* in_sizes, int n_in,
                              void* d_out, int out_size, void* d_ws, size_t ws_size,
                              hipStream_t stream) {
    const float* x    = (const float*)d_in[0];
    const float* phi  = (const float*)d_in[1];
    const float* W    = (const float*)d_in[2];
    const float* bias = (const float*)d_in[3];
    float* out = (float*)d_out;

    const int grid = (M_TOT / BM) * (N_TOT / BN);   // 2048
    const size_t ws_need = (size_t)N_TOT * K_TOT * sizeof(bf16_t);  // 512 KB

    if (ws_size >= ws_need) {
        bf16_t* Wws = (bf16_t*)d_ws;
        convert_W<<<(N_TOT * K_TOT / 8) / 256, 256, 0, stream>>>(W, Wws);
        qattn_fused_gemm<true><<<grid, 256, 0, stream>>>(x, phi, W, Wws, bias, out);
    } else {
        qattn_fused_gemm<false><<<grid, 256, 0, stream>>>(x, phi, W, nullptr, bias, out);
    }
}

// Round 6
// 77.461 us; speedup vs baseline: 1.2346x; 1.2346x over previous
//
#include <hip/hip_runtime.h>
#include <hip/hip_bf16.h>

typedef __bf16 bf16_t;
typedef bf16_t bf16x8 __attribute__((ext_vector_type(8)));
typedef float  f32x4  __attribute__((ext_vector_type(4)));

constexpr int M_TOT = 65536;   // B*S
constexpr int N_TOT = 512;     // E
constexpr int K_TOT = 512;     // E
constexpr int BM = 128, BN = 128, BK = 64;
constexpr int NT = K_TOT / BK; // 8 K-tiles

__device__ inline void gload_lds16(const void* g, void* l) {
    __builtin_amdgcn_global_load_lds(
        (const __attribute__((address_space(1))) void*)g,
        (__attribute__((address_space(3))) void*)l, 16, 0, 0);
}

// W (f32 [N][K]) -> bf16, chunk-XOR-swizzled: main kernel global_load_lds's it
// LINEARLY, reads back with chunk XOR. Wws[n][kt*64+(ck^(n&7))*8+j]=bf16(W[n][kt*64+ck*8+j])
__global__ __launch_bounds__(256)
void convert_W(const float* __restrict__ W, bf16_t* __restrict__ Wws)
{
    const int g  = blockIdx.x * 256 + threadIdx.x;
    const int n  = g >> 6;
    const int c  = g & 63;
    const int kt = c >> 3, ck = c & 7;
    const float4* src = reinterpret_cast<const float4*>(W + (size_t)n * K_TOT + c * 8);
    float4 v0 = src[0], v1 = src[1];
    bf16x8 b;
    b[0] = (bf16_t)v0.x; b[1] = (bf16_t)v0.y; b[2] = (bf16_t)v0.z; b[3] = (bf16_t)v0.w;
    b[4] = (bf16_t)v1.x; b[5] = (bf16_t)v1.y; b[6] = (bf16_t)v1.z; b[7] = (bf16_t)v1.w;
    const int dc = kt * 64 + ((ck ^ (n & 7)) * 8);
    *reinterpret_cast<bf16x8*>(Wws + (size_t)n * K_TOT + dc) = b;
}

// out[m,n] = sum_k cos(x[m,k] + phi[k%8]) * W[n,k] + bias[n]
// 8-wave (512-thread) block, 128x128 tile: per-thread acc = 32 f32 (half of the
// 4-wave version) -> ~100 regs/thread -> 2 blocks/CU = 16 waves/CU (50% occ),
// vs 12 waves at R4's 75us. Same proven 2-barrier A-in-LDS topology.
// R3 lesson: (256,5) spilled (FETCH 637MB). (512,4) caps regs at 128 w/ headroom.
template<bool USE_WS>
__global__ __launch_bounds__(512, 4)
void qattn_fused_gemm(const float* __restrict__ x,
                      const float* __restrict__ phi,
                      const float* __restrict__ W,
                      const bf16_t* __restrict__ Wws,
                      const float* __restrict__ bias,
                      float* __restrict__ out)
{
    __shared__ bf16_t As[BM][BK];   // 16 KB, XOR-swizzled
    __shared__ bf16_t Bs[BN][BK];   // 16 KB, XOR-swizzled image

    const int tid  = threadIdx.x;
    const int lane = tid & 63;
    const int wave = tid >> 6;      // 0..7

    // XCD-bijective swizzle: the 4 blocks sharing an x-panel on one XCD's L2.
    const int xcd = blockIdx.x & 7;
    const int idx = blockIdx.x >> 3;
    const int wid = xcd * 256 + idx;
    const int bm  = (wid >> 2) * BM;
    const int bn  = (wid & 3)  * BN;

    // A staging: thread t -> row t>>2, cols (t&3)*16 .. +15 (4 float4, contig)
    const int srow = tid >> 2;
    const int scol = (tid & 3) * 16;

    // phi for col scol+q*4+i: (scol+q*4+i)&7 = (q&1)*4+i
    float ph[8];
    #pragma unroll
    for (int j = 0; j < 8; ++j) ph[j] = phi[j];

    // wave grid 4M x 2N: wave owns 32 rows x 64 cols of the 128x128 tile
    const int wm   = (wave >> 1) * 32;
    const int wn   = (wave & 1) * 64;
    const int frow = lane & 15;
    const int fk   = (lane >> 4) * 8;

    f32x4  acc[2][4] = {};     // 32 f32/thread
    float4 pa[4];              // x(t) in flight: 16 contiguous floats of row srow

    const float* xrow = x + (size_t)(bm + srow) * K_TOT + scol;

    // ---- prologue: B(0) first (oldest in vmcnt FIFO), then x(0) ----
    if constexpr (USE_WS) {
        #pragma unroll
        for (int i = 0; i < 2; ++i) {
            const bf16_t* src = Wws + (size_t)(bn + wave * 16 + i * 8 + (lane >> 3)) * K_TOT
                                + (lane & 7) * 8;
            gload_lds16(src, &Bs[0][0] + wave * 1024 + i * 512);
        }
        __builtin_amdgcn_sched_barrier(0);
    } else {
        #pragma unroll
        for (int i = 0; i < 2; ++i) {
            const int ck = (tid & 3) * 2 + i;
            const int brow = tid >> 2;
            const float4* s = reinterpret_cast<const float4*>(
                W + (size_t)(bn + brow) * K_TOT + ck * 8);
            float4 v0 = s[0], v1 = s[1];
            bf16x8 b;
            b[0] = (bf16_t)v0.x; b[1] = (bf16_t)v0.y; b[2] = (bf16_t)v0.z; b[3] = (bf16_t)v0.w;
            b[4] = (bf16_t)v1.x; b[5] = (bf16_t)v1.y; b[6] = (bf16_t)v1.z; b[7] = (bf16_t)v1.w;
            *reinterpret_cast<bf16x8*>(&Bs[brow][(ck ^ (brow & 7)) * 8]) = b;
        }
    }
    #pragma unroll
    for (int q = 0; q < 4; ++q)
        pa[q] = *reinterpret_cast<const float4*>(xrow + q * 4);

    #pragma unroll
    for (int t = 0; t < NT; ++t) {
        const bool last = (t == NT - 1);
        const int  kn   = (t + 1) * BK;

        // ---- A(t): cos from prefetched regs -> LDS (2x ds_write_b128) ----
        #pragma unroll
        for (int j = 0; j < 2; ++j) {
            bf16x8 a;
            #pragma unroll
            for (int q = 0; q < 2; ++q) {
                const float4 v = pa[j * 2 + q];
                a[q * 4 + 0] = (bf16_t)__cosf(v.x + ph[(q & 1) * 4 + 0]);
                a[q * 4 + 1] = (bf16_t)__cosf(v.y + ph[(q & 1) * 4 + 1]);
                a[q * 4 + 2] = (bf16_t)__cosf(v.z + ph[(q & 1) * 4 + 2]);
                a[q * 4 + 3] = (bf16_t)__cosf(v.w + ph[(q & 1) * 4 + 3]);
            }
            const int c = (scol + j * 8) ^ ((srow & 7) << 3);
            *reinterpret_cast<bf16x8*>(&As[srow][c]) = a;
        }

        // ---- issue x(t+1): the ONLY vmem newer than B(t) at SYNC1 ----
        if (!last) {
            #pragma unroll
            for (int q = 0; q < 4; ++q)
                pa[q] = *reinterpret_cast<const float4*>(xrow + kn + q * 4);
        }

        // ---- SYNC1: drain B(t) (2 gloads; 4 newer x-loads stay in flight) ----
        if (USE_WS) {
            if (!last) asm volatile("s_waitcnt vmcnt(4) lgkmcnt(0)\n\ts_barrier" ::: "memory");
            else       asm volatile("s_waitcnt vmcnt(0) lgkmcnt(0)\n\ts_barrier" ::: "memory");
        } else {
            asm volatile("s_waitcnt lgkmcnt(0)\n\ts_barrier" ::: "memory");
        }

        // ---- compute: 4 af + 8 bfr ds_reads, 16 MFMAs ----
        #pragma unroll
        for (int kk = 0; kk < 2; ++kk) {
            bf16x8 af[2], bfr[4];
            #pragma unroll
            for (int mi = 0; mi < 2; ++mi) {
                const int r = wm + mi * 16 + frow;
                const int c = (kk * 32 + fk) ^ ((r & 7) << 3);
                af[mi] = *reinterpret_cast<bf16x8*>(&As[r][c]);
            }
            #pragma unroll
            for (int nj = 0; nj < 4; ++nj) {
                const int r = wn + nj * 16 + frow;
                const int c = (kk * 32 + fk) ^ ((r & 7) << 3);
                bfr[nj] = *reinterpret_cast<bf16x8*>(&Bs[r][c]);
            }
            #pragma unroll
            for (int mi = 0; mi < 2; ++mi)
                #pragma unroll
                for (int nj = 0; nj < 4; ++nj)
                    acc[mi][nj] = __builtin_amdgcn_mfma_f32_16x16x32_bf16(
                        af[mi], bfr[nj], acc[mi][nj], 0, 0, 0);
        }

        // ---- SYNC2 + stage B(t+1) (overwrites Bs -> must follow SYNC2) ----
        if (!last) {
            asm volatile("s_waitcnt lgkmcnt(0)\n\ts_barrier" ::: "memory");
            if constexpr (USE_WS) {
                #pragma unroll
                for (int i = 0; i < 2; ++i) {
                    const bf16_t* src = Wws
                        + (size_t)(bn + wave * 16 + i * 8 + (lane >> 3)) * K_TOT
                        + kn + (lane & 7) * 8;
                    gload_lds16(src, &Bs[0][0] + wave * 1024 + i * 512);
                }
                __builtin_amdgcn_sched_barrier(0);
            } else {
                #pragma unroll
                for (int i = 0; i < 2; ++i) {
                    const int ck = (tid & 3) * 2 + i;
                    const int brow = tid >> 2;
                    const float4* s = reinterpret_cast<const float4*>(
                        W + (size_t)(bn + brow) * K_TOT + kn + ck * 8);
                    float4 v0 = s[0], v1 = s[1];
                    bf16x8 b;
                    b[0] = (bf16_t)v0.x; b[1] = (bf16_t)v0.y; b[2] = (bf16_t)v0.z; b[3] = (bf16_t)v0.w;
                    b[4] = (bf16_t)v1.x; b[5] = (bf16_t)v1.y; b[6] = (bf16_t)v1.z; b[7] = (bf16_t)v1.w;
                    *reinterpret_cast<bf16x8*>(&Bs[brow][(ck ^ (brow & 7)) * 8]) = b;
                }
            }
        }
    }

    // ---- epilogue: C/D map col=lane&15, row=(lane>>4)*4+i ----
    #pragma unroll
    for (int nj = 0; nj < 4; ++nj) {
        const int c  = bn + wn + nj * 16 + frow;
        const float bv = bias[c];
        #pragma unroll
        for (int mi = 0; mi < 2; ++mi) {
            const int r0 = bm + wm + mi * 16 + (lane >> 4) * 4;
            #pragma unroll
            for (int i = 0; i < 4; ++i)
                out[(size_t)(r0 + i) * N_TOT + c] = acc[mi][nj][i] + bv;
        }
    }
}

extern "C" void kernel_launch(void* const* d_in, const int* in_sizes, int n_in,
                              void* d_out, int out_size, void* d_ws, size_t ws_size,
                              hipStream_t stream) {
    const float* x    = (const float*)d_in[0];
    const float* phi  = (const float*)d_in[1];
    const float* W    = (const float*)d_in[2];
    const float* bias = (const float*)d_in[3];
    float* out = (float*)d_out;

    const int grid = (M_TOT / BM) * (N_TOT / BN);   // 2048
    const size_t ws_need = (size_t)N_TOT * K_TOT * sizeof(bf16_t);  // 512 KB

    if (ws_size >= ws_need) {
        bf16_t* Wws = (bf16_t*)d_ws;
        convert_W<<<(N_TOT * K_TOT / 8) / 256, 256, 0, stream>>>(W, Wws);
        qattn_fused_gemm<true><<<grid, 512, 0, stream>>>(x, phi, W, Wws, bias, out);
    } else {
        qattn_fused_gemm<false><<<grid, 512, 0, stream>>>(x, phi, W, nullptr, bias, out);
    }
}